// Round 8
// baseline (197.775 us; speedup 1.0000x reference)
//
#include <hip/hip_runtime.h>
#include <hip/hip_bf16.h>
#include <stdint.h>

typedef __attribute__((ext_vector_type(8))) short s16x8;          // 8 bf16 (4 VGPRs)
typedef __attribute__((ext_vector_type(8))) unsigned short u16x8;
typedef __attribute__((ext_vector_type(4))) float f32x4;

#define D_FEAT 128
#define H2 128
#define BLOCK_THREADS 512
#define WAVES 8
#define MW 32                        // edges per wave (M-tile)
#define EPB (WAVES * MW)             // 256 edges per tile
#define TPB 4                        // tiles per block (rolling pipeline)

__device__ __forceinline__ unsigned short f2bf(float f) {
  uint32_t u = __float_as_uint(f);
  return (unsigned short)((u + 0x7fffu + ((u >> 16) & 1u)) >> 16);  // RNE
}

// ---------------- pre-conversion kernels ----------------
__global__ void k_cvt_x(const float* __restrict__ x, unsigned short* __restrict__ xb, int n8) {
  int i = blockIdx.x * blockDim.x + threadIdx.x;
  if (i >= n8) return;
  const f32x4* p = (const f32x4*)x + (size_t)i * 2;
  f32x4 a = p[0], b = p[1];
  u16x8 o;
  o[0] = f2bf(a[0]); o[1] = f2bf(a[1]); o[2] = f2bf(a[2]); o[3] = f2bf(a[3]);
  o[4] = f2bf(b[0]); o[5] = f2bf(b[1]); o[6] = f2bf(b[2]); o[7] = f2bf(b[3]);
  ((u16x8*)xb)[i] = o;
}

// W1 [256][128] fp32 -> bf16 "fragment-sequential" image (64KB) in ws.
// Chunk index = (kk*8 + f)*64 + lane, lane = (g<<4)|c. Chunk holds the 8
// B-frag elements j: W1[k = kk*32 + g*8 + j][n = f*16 + c].
// Wave read of (kk,f) = base + lane*16B, 1KB contiguous: conflict-free, no VALU.
__global__ void k_cvt_w1(const float* __restrict__ W1, unsigned short* __restrict__ w1s) {
  int tid = blockIdx.x * blockDim.x + threadIdx.x;   // 0..4095
  int lane = tid & 63;
  int kkf  = tid >> 6;        // kk*8 + f
  int kk = kkf >> 3, f = kkf & 7;
  int c = lane & 15, g = lane >> 4;
  int n = f * 16 + c;
  u16x8 o;
#pragma unroll
  for (int j = 0; j < 8; ++j)
    o[j] = f2bf(W1[(kk * 32 + g * 8 + j) * H2 + n]);
  ((u16x8*)w1s)[tid] = o;
}

// ---------------- main fused kernel ----------------
template <bool XBF>
__global__ __launch_bounds__(BLOCK_THREADS, 4)   // 4 waves/SIMD => 2 blocks/CU
void k_edge_mlp(const float* __restrict__ xf,
                const unsigned short* __restrict__ xb,
                const int* __restrict__ eli,      // int32: [2][E]
                const float* __restrict__ W1,
                const unsigned short* __restrict__ w1ws,
                const float* __restrict__ b1,
                const float* __restrict__ W2,
                const float* __restrict__ b2,
                float* __restrict__ out, int E, int nNodes)
{
  __shared__ alignas(16) unsigned short w1t[H2 * 256];   // 64KB fragment-sequential
  const int t0   = threadIdx.x;
  const int lane = t0 & 63;
  const int wid  = t0 >> 6;
  const int c    = lane & 15;   // A-row-in-frag / B-col-in-frag
  const int g    = lane >> 4;   // k-subgroup (8 consecutive k)

  // ---- stage W1 image into LDS (once per block) ----
  if (XBF) {
#pragma unroll
    for (int i = 0; i < 8; ++i) {
      int idx = i * BLOCK_THREADS + t0;             // 4096 chunks of 16B, linear
      ((u16x8*)w1t)[idx] = ((const u16x8*)w1ws)[idx];
    }
  } else {
#pragma unroll
    for (int i = 0; i < 8; ++i) {
      int chunk = i * BLOCK_THREADS + t0;           // 0..4095
      int cl  = chunk & 63;
      int kkf = chunk >> 6;
      int kk = kkf >> 3, f = kkf & 7;
      int cc = cl & 15, gg = cl >> 4;
      int n = f * 16 + cc;
      u16x8 o;
#pragma unroll
      for (int j = 0; j < 8; ++j)
        o[j] = f2bf(W1[(kk * 32 + gg * 8 + j) * H2 + n]);
      ((u16x8*)w1t)[chunk] = o;
    }
  }

  const int nt = (E + EPB - 1) / EPB;
  int tile = blockIdx.x * TPB;
  if (tile >= nt) return;
  const int tend = (tile + TPB < nt) ? tile + TPB : nt;

  // edge-index -> node element offsets (g*8 folded in)
  auto mkoff = [&](int tt, unsigned* ro, unsigned* co) {
#pragma unroll
    for (int m = 0; m < 2; ++m) {
      int e = tt * EPB + wid * MW + m * 16 + c;
      e = e < E ? e : E - 1;
      int nr = eli[e];
      int nc = eli[E + e];
      nr = nr < 0 ? 0 : (nr >= nNodes ? nNodes - 1 : nr);   // defensive clamp
      nc = nc < 0 ? 0 : (nc >= nNodes ? nNodes - 1 : nc);
      ro[m] = (unsigned)nr * D_FEAT + g * 8;
      co[m] = (unsigned)nc * D_FEAT + g * 8;
    }
  };

  auto loadA = [&](const unsigned* ro, const unsigned* co, int kk, s16x8* dst) {
#pragma unroll
    for (int m = 0; m < 2; ++m) {
      unsigned off = (kk < 4 ? ro[m] : co[m]) + (unsigned)((kk & 3) * 32);
      if (XBF) {
        dst[m] = *(const s16x8*)(xb + off);
      } else {
        const f32x4* q = (const f32x4*)(xf + off);
        f32x4 a = q[0], b = q[1];
        s16x8 v;
        v[0] = (short)f2bf(a[0]); v[1] = (short)f2bf(a[1]);
        v[2] = (short)f2bf(a[2]); v[3] = (short)f2bf(a[3]);
        v[4] = (short)f2bf(b[0]); v[5] = (short)f2bf(b[1]);
        v[6] = (short)f2bf(b[2]); v[7] = (short)f2bf(b[3]);
        dst[m] = v;
      }
    }
  };

  __syncthreads();   // W1 staged — the ONLY barrier in the kernel

  // single shared LDS base; every B read = base + compile-time offset
  const unsigned short* bbase = w1t + (unsigned)lane * 8;   // lane*16B

  // rolling state: offsets + depth-2 A pipeline, carried ACROSS tiles
  unsigned ro[2], co[2];
  mkoff(tile, ro, co);
  s16x8 abuf[2][2];
  loadA(ro, co, 0, abuf[0]);
  loadA(ro, co, 1, abuf[1]);

  const float b2s = b2[0];

  while (true) {
    f32x4 acc[2][8];
#pragma unroll
    for (int m = 0; m < 2; ++m)
#pragma unroll
      for (int f = 0; f < 8; ++f) {
        f32x4 z = {0.f, 0.f, 0.f, 0.f};
        acc[m][f] = z;
      }

#pragma unroll
    for (int kk = 0; kk < 8; ++kk) {
      __builtin_amdgcn_s_setprio(1);
#pragma unroll
      for (int f = 0; f < 8; ++f) {
        s16x8 bfrag = *(const s16x8*)(bbase + (kk * 8 + f) * 512);  // offset:(kk*8+f)*1024B
#pragma unroll
        for (int m = 0; m < 2; ++m)
          acc[m][f] = __builtin_amdgcn_mfma_f32_16x16x32_bf16(abuf[kk & 1][m], bfrag, acc[m][f], 0, 0, 0);
      }
      __builtin_amdgcn_s_setprio(0);
      if (kk < 6) loadA(ro, co, kk + 2, abuf[kk & 1]);   // same-tile refill
    }

    // ---- phase 1: pre-reduce acc -> pre[2][4] (FREES all 64 acc regs) ----
    float b1v[8], w2v[8];
#pragma unroll
    for (int f = 0; f < 8; ++f) {
      b1v[f] = b1[f * 16 + c];     // L1-resident reloads
      w2v[f] = W2[f * 16 + c];
    }
    float pre[2][4];
#pragma unroll
    for (int m = 0; m < 2; ++m)
#pragma unroll
      for (int r = 0; r < 4; ++r) {
        float s = 0.f;
#pragma unroll
        for (int f = 0; f < 8; ++f) {
          float h = acc[m][f][r] + b1v[f];
          h = h > 0.f ? h : 0.f;
          s += h * w2v[f];
        }
        pre[m][r] = s;
      }

    const int gbase = tile * EPB + wid * MW;     // current tile's output base
    const bool more = (tile + 1 < tend);

    // ---- phase 2: next tile's eli + first gathers go in flight NOW ----
    if (more) {
      mkoff(tile + 1, ro, co);
      loadA(ro, co, 0, abuf[0]);
      loadA(ro, co, 1, abuf[1]);
    }

    // ---- phase 3: shfl-reduce + store (covers the in-flight gathers) ----
#pragma unroll
    for (int m = 0; m < 2; ++m) {
      float sr[4];
#pragma unroll
      for (int r = 0; r < 4; ++r) {
        float s = pre[m][r];
#pragma unroll
        for (int msk = 1; msk < 16; msk <<= 1)
          s += __shfl_xor(s, msk, 64);   // reduce over the 16 c-lanes
        sr[r] = s;
      }
      int ebase = gbase + m * 16 + g * 4;
      if (c == 0 && ebase < E) {
        f32x4 o = {sr[0] + b2s, sr[1] + b2s, sr[2] + b2s, sr[3] + b2s};
        *(f32x4*)(out + ebase) = o;
      }
    }

    if (!more) break;
    ++tile;
  }
}

extern "C" void kernel_launch(void* const* d_in, const int* in_sizes, int n_in,
                              void* d_out, int out_size, void* d_ws, size_t ws_size,
                              hipStream_t stream) {
  const float* x   = (const float*)d_in[0];
  const int*   eli = (const int*)d_in[1];     // int32 per harness contract
  const float* W1  = (const float*)d_in[2];
  const float* b1  = (const float*)d_in[3];
  const float* W2  = (const float*)d_in[4];
  const float* b2  = (const float*)d_in[5];
  float* out = (float*)d_out;

  const int E      = in_sizes[1] / 2;
  const int nNodes = in_sizes[0] / D_FEAT;

  const size_t xbytes = (size_t)nNodes * D_FEAT * 2;   // bf16 copy of x
  const size_t need   = xbytes + 65536;                // + W1 fragment image
  const bool bfpath   = (ws_size >= need);

  const int nt   = (E + EPB - 1) / EPB;
  const int grid = (nt + TPB - 1) / TPB;

  if (bfpath) {
    unsigned short* xbw  = (unsigned short*)d_ws;
    unsigned short* w1sw = (unsigned short*)((char*)d_ws + xbytes);
    int n8 = nNodes * D_FEAT / 8;
    k_cvt_x<<<(n8 + 255) / 256, 256, 0, stream>>>(x, xbw, n8);
    k_cvt_w1<<<16, 256, 0, stream>>>(W1, w1sw);
    k_edge_mlp<true><<<grid, BLOCK_THREADS, 0, stream>>>(
        x, xbw, eli, W1, w1sw, b1, W2, b2, out, E, nNodes);
  } else {
    k_edge_mlp<false><<<grid, BLOCK_THREADS, 0, stream>>>(
        x, nullptr, eli, W1, nullptr, b1, W2, b2, out, E, nNodes);
  }
}

// Round 9
// 158.539 us; speedup vs baseline: 1.2475x; 1.2475x over previous
//
#include <hip/hip_runtime.h>
#include <hip/hip_bf16.h>
#include <stdint.h>

typedef __attribute__((ext_vector_type(8))) short s16x8;          // 8 bf16 (4 VGPRs)
typedef __attribute__((ext_vector_type(8))) unsigned short u16x8;
typedef __attribute__((ext_vector_type(4))) float f32x4;

#define D_FEAT 128
#define H2 128
#define BLOCK_THREADS 512
#define WAVES 8
#define MW 64                        // edges per wave (M-tile) — 2-wave/SIMD regime
#define EPB (WAVES * MW)             // 512 edges per block

__device__ __forceinline__ unsigned short f2bf(float f) {
  uint32_t u = __float_as_uint(f);
  return (unsigned short)((u + 0x7fffu + ((u >> 16) & 1u)) >> 16);  // RNE
}

// ---------------- pre-conversion kernels ----------------
__global__ void k_cvt_x(const float* __restrict__ x, unsigned short* __restrict__ xb, int n8) {
  int i = blockIdx.x * blockDim.x + threadIdx.x;
  if (i >= n8) return;
  const f32x4* p = (const f32x4*)x + (size_t)i * 2;
  f32x4 a = p[0], b = p[1];
  u16x8 o;
  o[0] = f2bf(a[0]); o[1] = f2bf(a[1]); o[2] = f2bf(a[2]); o[3] = f2bf(a[3]);
  o[4] = f2bf(b[0]); o[5] = f2bf(b[1]); o[6] = f2bf(b[2]); o[7] = f2bf(b[3]);
  ((u16x8*)xb)[i] = o;
}

// W1 [256][128] fp32 -> bf16 "fragment-sequential" image (64KB) in ws.
// Chunk index = (kk*8 + f)*64 + lane, lane = (g<<4)|c. Chunk holds the 8
// B-frag elements j: W1[k = kk*32 + g*8 + j][n = f*16 + c].
// Wave read of (kk,f) = base + lane*16B, 1KB contiguous: conflict-free, no VALU.
__global__ void k_cvt_w1(const float* __restrict__ W1, unsigned short* __restrict__ w1s) {
  int tid = blockIdx.x * blockDim.x + threadIdx.x;   // 0..4095
  int lane = tid & 63;
  int kkf  = tid >> 6;        // kk*8 + f
  int kk = kkf >> 3, f = kkf & 7;
  int c = lane & 15, g = lane >> 4;
  int n = f * 16 + c;
  u16x8 o;
#pragma unroll
  for (int j = 0; j < 8; ++j)
    o[j] = f2bf(W1[(kk * 32 + g * 8 + j) * H2 + n]);
  ((u16x8*)w1s)[tid] = o;
}

// ---------------- main fused kernel ----------------
template <bool XBF>
__global__ __launch_bounds__(BLOCK_THREADS, 2)   // 2 waves/SIMD band (<=256 regs)
void k_edge_mlp(const float* __restrict__ xf,
                const unsigned short* __restrict__ xb,
                const int* __restrict__ eli,      // int32: [2][E]
                const float* __restrict__ W1,
                const unsigned short* __restrict__ w1ws,
                const float* __restrict__ b1,
                const float* __restrict__ W2,
                const float* __restrict__ b2,
                float* __restrict__ out, int E, int nNodes)
{
  __shared__ alignas(16) unsigned short w1t[H2 * 256];   // 64KB fragment-sequential
  const int t0   = threadIdx.x;
  const int lane = t0 & 63;
  const int wid  = t0 >> 6;
  const int c    = lane & 15;   // A-row-in-frag / B-col-in-frag
  const int g    = lane >> 4;   // k-subgroup (8 consecutive k)

  // ---- stage W1 image into LDS ----
  if (XBF) {
#pragma unroll
    for (int i = 0; i < 8; ++i) {
      int idx = i * BLOCK_THREADS + t0;             // 4096 chunks of 16B, linear
      ((u16x8*)w1t)[idx] = ((const u16x8*)w1ws)[idx];
    }
  } else {
#pragma unroll
    for (int i = 0; i < 8; ++i) {
      int chunk = i * BLOCK_THREADS + t0;           // 0..4095
      int cl  = chunk & 63;
      int kkf = chunk >> 6;
      int kk = kkf >> 3, f = kkf & 7;
      int cc = cl & 15, gg = cl >> 4;
      int n = f * 16 + cc;
      u16x8 o;
#pragma unroll
      for (int j = 0; j < 8; ++j)
        o[j] = f2bf(W1[(kk * 32 + gg * 8 + j) * H2 + n]);
      ((u16x8*)w1t)[chunk] = o;
    }
  }

  // ---- per-lane edge node offsets (4 edges per lane: m=0..3) ----
  const int gbase = blockIdx.x * EPB + wid * MW;
  unsigned ro[4], co[4];
#pragma unroll
  for (int m = 0; m < 4; ++m) {
    int e = gbase + m * 16 + c;
    e = e < E ? e : E - 1;
    int nr = eli[e];
    int nc = eli[E + e];
    nr = nr < 0 ? 0 : (nr >= nNodes ? nNodes - 1 : nr);   // defensive clamp
    nc = nc < 0 ? 0 : (nc >= nNodes ? nNodes - 1 : nc);
    ro[m] = (unsigned)nr * D_FEAT + g * 8;
    co[m] = (unsigned)nc * D_FEAT + g * 8;
  }

  // b1 folded into accumulator init (MFMA C-in is the bias — free adds)
  float b1v[8];
#pragma unroll
  for (int f = 0; f < 8; ++f) b1v[f] = b1[f * 16 + c];

  __syncthreads();

  // A-fragment gather: kk selects 32-wide K slice; kk<4 -> row node, else col node
  auto loadA = [&](int kk, s16x8* dst) {
#pragma unroll
    for (int m = 0; m < 4; ++m) {
      unsigned off = (kk < 4 ? ro[m] : co[m]) + (unsigned)((kk & 3) * 32);
      if (XBF) {
        dst[m] = *(const s16x8*)(xb + off);
      } else {
        const f32x4* q = (const f32x4*)(xf + off);
        f32x4 a = q[0], b = q[1];
        s16x8 v;
        v[0] = (short)f2bf(a[0]); v[1] = (short)f2bf(a[1]);
        v[2] = (short)f2bf(a[2]); v[3] = (short)f2bf(a[3]);
        v[4] = (short)f2bf(b[0]); v[5] = (short)f2bf(b[1]);
        v[6] = (short)f2bf(b[2]); v[7] = (short)f2bf(b[3]);
        dst[m] = v;
      }
    }
  };

  f32x4 acc[4][8];
#pragma unroll
  for (int m = 0; m < 4; ++m)
#pragma unroll
    for (int f = 0; f < 8; ++f) {
      f32x4 z = {b1v[f], b1v[f], b1v[f], b1v[f]};
      acc[m][f] = z;
    }

  // depth-2 A pipeline; ~40 spare regs left for the scheduler to hoist B ds_reads
  s16x8 abuf[2][4];
  loadA(0, abuf[0]);
  loadA(1, abuf[1]);

  // single shared LDS base; every B read = base + compile-time offset
  const unsigned short* bbase = w1t + (unsigned)lane * 8;   // lane*16B

#pragma unroll
  for (int kk = 0; kk < 8; ++kk) {
    __builtin_amdgcn_s_setprio(1);
#pragma unroll
    for (int f = 0; f < 8; ++f) {
      s16x8 bfrag = *(const s16x8*)(bbase + (kk * 8 + f) * 512);  // offset:(kk*8+f)*1024B
#pragma unroll
      for (int m = 0; m < 4; ++m)
        acc[m][f] = __builtin_amdgcn_mfma_f32_16x16x32_bf16(abuf[kk & 1][m], bfrag, acc[m][f], 0, 0, 0);
    }
    __builtin_amdgcn_s_setprio(0);
    if (kk < 6) loadA(kk + 2, abuf[kk & 1]);   // refill slot consumed this iteration
  }

  // ---- fused epilogue: relu(h) @ W2 + b2 (bias already in acc), fp32 ----
  float w2v[8];
#pragma unroll
  for (int f = 0; f < 8; ++f) w2v[f] = W2[f * 16 + c];
  const float b2s = b2[0];

#pragma unroll
  for (int m = 0; m < 4; ++m) {
    float sr[4];
#pragma unroll
    for (int r = 0; r < 4; ++r) {
      float s = 0.f;
#pragma unroll
      for (int f = 0; f < 8; ++f) {
        float h = acc[m][f][r];
        h = h > 0.f ? h : 0.f;
        s += h * w2v[f];
      }
#pragma unroll
      for (int msk = 1; msk < 16; msk <<= 1)
        s += __shfl_xor(s, msk, 64);   // reduce over the 16 c-lanes
      sr[r] = s;
    }
    int ebase = gbase + m * 16 + g * 4;
    if (c == 0 && ebase < E) {
      f32x4 o = {sr[0] + b2s, sr[1] + b2s, sr[2] + b2s, sr[3] + b2s};
      *(f32x4*)(out + ebase) = o;
    }
  }
}

extern "C" void kernel_launch(void* const* d_in, const int* in_sizes, int n_in,
                              void* d_out, int out_size, void* d_ws, size_t ws_size,
                              hipStream_t stream) {
  const float* x   = (const float*)d_in[0];
  const int*   eli = (const int*)d_in[1];     // int32 per harness contract
  const float* W1  = (const float*)d_in[2];
  const float* b1  = (const float*)d_in[3];
  const float* W2  = (const float*)d_in[4];
  const float* b2  = (const float*)d_in[5];
  float* out = (float*)d_out;

  const int E      = in_sizes[1] / 2;
  const int nNodes = in_sizes[0] / D_FEAT;

  const size_t xbytes = (size_t)nNodes * D_FEAT * 2;   // bf16 copy of x
  const size_t need   = xbytes + 65536;                // + W1 fragment image
  const bool bfpath   = (ws_size >= need);

  const int grid = (E + EPB - 1) / EPB;

  if (bfpath) {
    unsigned short* xbw  = (unsigned short*)d_ws;
    unsigned short* w1sw = (unsigned short*)((char*)d_ws + xbytes);
    int n8 = nNodes * D_FEAT / 8;
    k_cvt_x<<<(n8 + 255) / 256, 256, 0, stream>>>(x, xbw, n8);
    k_cvt_w1<<<16, 256, 0, stream>>>(W1, w1sw);
    k_edge_mlp<true><<<grid, BLOCK_THREADS, 0, stream>>>(
        x, xbw, eli, W1, w1sw, b1, W2, b2, out, E, nNodes);
  } else {
    k_edge_mlp<false><<<grid, BLOCK_THREADS, 0, stream>>>(
        x, nullptr, eli, W1, nullptr, b1, W2, b2, out, E, nNodes);
  }
}

// Round 10
// 148.172 us; speedup vs baseline: 1.3348x; 1.0700x over previous
//
#include <hip/hip_runtime.h>
#include <hip/hip_bf16.h>
#include <stdint.h>

typedef __attribute__((ext_vector_type(8))) short s16x8;          // 8 bf16 (4 VGPRs)
typedef __attribute__((ext_vector_type(8))) unsigned short u16x8;
typedef __attribute__((ext_vector_type(4))) float f32x4;

#define D_FEAT 128
#define H2 128

__device__ __forceinline__ unsigned short f2bf(float f) {
  uint32_t u = __float_as_uint(f);
  return (unsigned short)((u + 0x7fffu + ((u >> 16) & 1u)) >> 16);  // RNE
}
__device__ __forceinline__ float bf2f(unsigned short s) {
  return __uint_as_float((uint32_t)s << 16);
}

// W1 [256][128] fp32 -> bf16 "fragment-sequential" image (64KB) in ws.
// Chunk index = (kk*8 + f)*64 + lane, lane = (g<<4)|c. Chunk holds the 8
// B-frag elements j: W1[k = kk*32 + g*8 + j][n = f*16 + c].  (R7-verified)
__global__ void k_cvt_w1(const float* __restrict__ W1, unsigned short* __restrict__ w1s) {
  int tid = blockIdx.x * blockDim.x + threadIdx.x;   // 0..4095
  int lane = tid & 63;
  int kkf  = tid >> 6;        // kk*8 + f
  int kk = kkf >> 3, f = kkf & 7;
  int c = lane & 15, g = lane >> 4;
  int n = f * 16 + c;
  u16x8 o;
#pragma unroll
  for (int j = 0; j < 8; ++j)
    o[j] = f2bf(W1[(kk * 32 + g * 8 + j) * H2 + n]);
  ((u16x8*)w1s)[tid] = o;
}

// Permuted W2 (f32): stored position s = c*8+f  <->  logical n = f*16+c.
// Matches the u/v storage permutation so the edge-stage dot is order-invariant.
__global__ void k_cvt_w2p(const float* __restrict__ W2, float* __restrict__ w2p) {
  int s = threadIdx.x;   // 0..127
  w2p[s] = W2[(s & 7) * 16 + (s >> 3)];
}

// ---------------- node precompute: u = x@W1a + b1, v = x@W1b (bf16, permuted cols) ----
__global__ __launch_bounds__(256, 4)
void k_uv(const float* __restrict__ x,
          const unsigned short* __restrict__ w1ws,
          const float* __restrict__ b1,
          unsigned short* __restrict__ u,
          unsigned short* __restrict__ v,
          int nNodes)
{
  __shared__ alignas(16) unsigned short w1t[H2 * 256];   // 64KB fragment image
  const int t0 = threadIdx.x, lane = t0 & 63, wid = t0 >> 6;
  const int c = lane & 15, g = lane >> 4;

#pragma unroll
  for (int i = 0; i < 16; ++i) {
    int idx = i * 256 + t0;
    ((u16x8*)w1t)[idx] = ((const u16x8*)w1ws)[idx];
  }

  const int nb = blockIdx.x * 128 + wid * 32;
  // A-frags: x rows (coalesced), full K=128 held (32 regs)
  s16x8 af[4][2];
#pragma unroll
  for (int m = 0; m < 2; ++m) {
    int node = nb + m * 16 + c;
    node = node < nNodes ? node : nNodes - 1;
    const float* xp = x + (size_t)node * D_FEAT;
#pragma unroll
    for (int kk = 0; kk < 4; ++kk) {
      const f32x4* q = (const f32x4*)(xp + kk * 32 + g * 8);
      f32x4 a = q[0], b = q[1];
      s16x8 vv;
      vv[0] = (short)f2bf(a[0]); vv[1] = (short)f2bf(a[1]);
      vv[2] = (short)f2bf(a[2]); vv[3] = (short)f2bf(a[3]);
      vv[4] = (short)f2bf(b[0]); vv[5] = (short)f2bf(b[1]);
      vv[6] = (short)f2bf(b[2]); vv[7] = (short)f2bf(b[3]);
      af[kk][m] = vv;
    }
  }
  float b1v[8];
#pragma unroll
  for (int f = 0; f < 8; ++f) b1v[f] = b1[f * 16 + c];

  __syncthreads();
  const unsigned short* bbase = w1t + (unsigned)lane * 8;   // lane*16B

  f32x4 acc[2][8];

  // ---- u pass: acc init = b1 (C-in is the bias), K chunks 0..3 ----
#pragma unroll
  for (int m = 0; m < 2; ++m)
#pragma unroll
    for (int f = 0; f < 8; ++f) {
      f32x4 z = {b1v[f], b1v[f], b1v[f], b1v[f]};
      acc[m][f] = z;
    }
#pragma unroll
  for (int kk = 0; kk < 4; ++kk)
#pragma unroll
    for (int f = 0; f < 8; ++f) {
      s16x8 bfrag = *(const s16x8*)(bbase + (kk * 8 + f) * 512);
#pragma unroll
      for (int m = 0; m < 2; ++m)
        acc[m][f] = __builtin_amdgcn_mfma_f32_16x16x32_bf16(af[kk][m], bfrag, acc[m][f], 0, 0, 0);
    }
#pragma unroll
  for (int m = 0; m < 2; ++m)
#pragma unroll
    for (int r = 0; r < 4; ++r) {
      int node = nb + m * 16 + g * 4 + r;     // D row = g*4+r within 16-tile
      if (node < nNodes) {
        u16x8 o;
#pragma unroll
        for (int f = 0; f < 8; ++f) o[f] = f2bf(acc[m][f][r]);
        *(u16x8*)(u + (size_t)node * H2 + c * 8) = o;   // stored cols c*8..c*8+7
      }
    }

  // ---- v pass: acc init = 0, K chunks 4..7 (same x A-frags) ----
#pragma unroll
  for (int m = 0; m < 2; ++m)
#pragma unroll
    for (int f = 0; f < 8; ++f) {
      f32x4 z = {0.f, 0.f, 0.f, 0.f};
      acc[m][f] = z;
    }
#pragma unroll
  for (int kk = 0; kk < 4; ++kk)
#pragma unroll
    for (int f = 0; f < 8; ++f) {
      s16x8 bfrag = *(const s16x8*)(bbase + ((kk + 4) * 8 + f) * 512);
#pragma unroll
      for (int m = 0; m < 2; ++m)
        acc[m][f] = __builtin_amdgcn_mfma_f32_16x16x32_bf16(af[kk][m], bfrag, acc[m][f], 0, 0, 0);
    }
#pragma unroll
  for (int m = 0; m < 2; ++m)
#pragma unroll
    for (int r = 0; r < 4; ++r) {
      int node = nb + m * 16 + g * 4 + r;
      if (node < nNodes) {
        u16x8 o;
#pragma unroll
        for (int f = 0; f < 8; ++f) o[f] = f2bf(acc[m][f][r]);
        *(u16x8*)(v + (size_t)node * H2 + c * 8) = o;
      }
    }
}

// ---------------- edge stage: out[e] = relu(u[r]+v[c]) . w2p + b2 ----------------
// Wave = 16 edges (c = edge), 4 g-lanes per edge each own 32 stored h-positions.
// No LDS, no barrier, no MFMA: pure gather + VALU, max occupancy.
__global__ __launch_bounds__(256, 8)
void k_edge(const unsigned short* __restrict__ u,
            const unsigned short* __restrict__ v,
            const int* __restrict__ eli,
            const float* __restrict__ w2p,
            const float* __restrict__ b2,
            float* __restrict__ out, int E, int nNodes)
{
  const int t0 = threadIdx.x, lane = t0 & 63, wid = t0 >> 6;
  const int c = lane & 15, g = lane >> 4;
  const int ebase = blockIdx.x * 64 + wid * 16;

  int e = ebase + c;
  e = e < E ? e : E - 1;
  int nr = eli[e], nc = eli[E + e];
  nr = nr < 0 ? 0 : (nr >= nNodes ? nNodes - 1 : nr);
  nc = nc < 0 ? 0 : (nc >= nNodes ? nNodes - 1 : nc);
  const unsigned short* up = u + (size_t)nr * H2 + g * 8;
  const unsigned short* vp = v + (size_t)nc * H2 + g * 8;

  // all 8 gathers issued up front (16B per lane; 4 g-lanes = 64B/node segment)
  u16x8 uu[4], vv[4];
#pragma unroll
  for (int kk = 0; kk < 4; ++kk) {
    uu[kk] = *(const u16x8*)(up + kk * 32);
    vv[kk] = *(const u16x8*)(vp + kk * 32);
  }

  float s = 0.f;
#pragma unroll
  for (int kk = 0; kk < 4; ++kk) {
    const f32x4* wq = (const f32x4*)(w2p + kk * 32 + g * 8);
    f32x4 w0 = wq[0], w1 = wq[1];
#pragma unroll
    for (int j = 0; j < 8; ++j) {
      float h = bf2f(uu[kk][j]) + bf2f(vv[kk][j]);
      h = h > 0.f ? h : 0.f;
      float w = (j < 4) ? w0[j & 3] : w1[j & 3];
      s += h * w;
    }
  }
  // reduce over the 4 g-lanes of each edge
  s += __shfl_xor(s, 16, 64);
  s += __shfl_xor(s, 32, 64);
  if (g == 0) {
    int eo = ebase + c;
    if (eo < E) out[eo] = s + b2[0];
  }
}

// ---------------- fallback (ws too small): R7 monolithic, fp32 paths ----------------
__global__ __launch_bounds__(512, 4)
void k_fallback(const float* __restrict__ xf,
                const int* __restrict__ eli,
                const float* __restrict__ W1,
                const float* __restrict__ b1,
                const float* __restrict__ W2,
                const float* __restrict__ b2,
                float* __restrict__ out, int E, int nNodes)
{
  __shared__ alignas(16) unsigned short w1t[H2 * 256];
  const int t0 = threadIdx.x, lane = t0 & 63, wid = t0 >> 6;
  const int c = lane & 15, g = lane >> 4;

#pragma unroll
  for (int i = 0; i < 8; ++i) {
    int chunk = i * 512 + t0;
    int cl = chunk & 63, kkf = chunk >> 6;
    int kk = kkf >> 3, f = kkf & 7;
    int cc = cl & 15, gg = cl >> 4;
    int n = f * 16 + cc;
    u16x8 o;
#pragma unroll
    for (int j = 0; j < 8; ++j)
      o[j] = f2bf(W1[(kk * 32 + gg * 8 + j) * H2 + n]);
    ((u16x8*)w1t)[chunk] = o;
  }

  const int gbase = blockIdx.x * 256 + wid * 32;
  unsigned ro[2], co[2];
#pragma unroll
  for (int m = 0; m < 2; ++m) {
    int e = gbase + m * 16 + c;
    e = e < E ? e : E - 1;
    int nr = eli[e], nc = eli[E + e];
    nr = nr < 0 ? 0 : (nr >= nNodes ? nNodes - 1 : nr);
    nc = nc < 0 ? 0 : (nc >= nNodes ? nNodes - 1 : nc);
    ro[m] = (unsigned)nr * D_FEAT + g * 8;
    co[m] = (unsigned)nc * D_FEAT + g * 8;
  }
  __syncthreads();

  auto loadA = [&](int kk, s16x8* dst) {
#pragma unroll
    for (int m = 0; m < 2; ++m) {
      unsigned off = (kk < 4 ? ro[m] : co[m]) + (unsigned)((kk & 3) * 32);
      const f32x4* q = (const f32x4*)(xf + off);
      f32x4 a = q[0], b = q[1];
      s16x8 vv2;
      vv2[0] = (short)f2bf(a[0]); vv2[1] = (short)f2bf(a[1]);
      vv2[2] = (short)f2bf(a[2]); vv2[3] = (short)f2bf(a[3]);
      vv2[4] = (short)f2bf(b[0]); vv2[5] = (short)f2bf(b[1]);
      vv2[6] = (short)f2bf(b[2]); vv2[7] = (short)f2bf(b[3]);
      dst[m] = vv2;
    }
  };

  f32x4 acc[2][8];
#pragma unroll
  for (int m = 0; m < 2; ++m)
#pragma unroll
    for (int f = 0; f < 8; ++f) {
      f32x4 z = {0.f, 0.f, 0.f, 0.f};
      acc[m][f] = z;
    }
  s16x8 abuf[2][2];
  loadA(0, abuf[0]);
  loadA(1, abuf[1]);
  const unsigned short* bbase = w1t + (unsigned)lane * 8;
#pragma unroll
  for (int kk = 0; kk < 8; ++kk) {
#pragma unroll
    for (int f = 0; f < 8; ++f) {
      s16x8 bfrag = *(const s16x8*)(bbase + (kk * 8 + f) * 512);
#pragma unroll
      for (int m = 0; m < 2; ++m)
        acc[m][f] = __builtin_amdgcn_mfma_f32_16x16x32_bf16(abuf[kk & 1][m], bfrag, acc[m][f], 0, 0, 0);
    }
    if (kk < 6) loadA(kk + 2, abuf[kk & 1]);
  }
  float b1v[8], w2v[8];
#pragma unroll
  for (int f = 0; f < 8; ++f) { b1v[f] = b1[f * 16 + c]; w2v[f] = W2[f * 16 + c]; }
  const float b2s = b2[0];
#pragma unroll
  for (int m = 0; m < 2; ++m) {
    float sr[4];
#pragma unroll
    for (int r = 0; r < 4; ++r) {
      float s = 0.f;
#pragma unroll
      for (int f = 0; f < 8; ++f) {
        float h = acc[m][f][r] + b1v[f];
        h = h > 0.f ? h : 0.f;
        s += h * w2v[f];
      }
#pragma unroll
      for (int msk = 1; msk < 16; msk <<= 1) s += __shfl_xor(s, msk, 64);
      sr[r] = s;
    }
    int ebase2 = gbase + m * 16 + g * 4;
    if (c == 0 && ebase2 < E) {
      f32x4 o = {sr[0] + b2s, sr[1] + b2s, sr[2] + b2s, sr[3] + b2s};
      *(f32x4*)(out + ebase2) = o;
    }
  }
}

extern "C" void kernel_launch(void* const* d_in, const int* in_sizes, int n_in,
                              void* d_out, int out_size, void* d_ws, size_t ws_size,
                              hipStream_t stream) {
  const float* x   = (const float*)d_in[0];
  const int*   eli = (const int*)d_in[1];     // int32 per harness contract
  const float* W1  = (const float*)d_in[2];
  const float* b1  = (const float*)d_in[3];
  const float* W2  = (const float*)d_in[4];
  const float* b2  = (const float*)d_in[5];
  float* out = (float*)d_out;

  const int E      = in_sizes[1] / 2;
  const int nNodes = in_sizes[0] / D_FEAT;

  const size_t ubytes = (size_t)nNodes * H2 * 2;      // 25.6MB each
  const size_t need   = 2 * ubytes + 65536 + 512;

  if (ws_size >= need) {
    unsigned short* us  = (unsigned short*)d_ws;
    unsigned short* vs  = (unsigned short*)((char*)d_ws + ubytes);
    unsigned short* w1f = (unsigned short*)((char*)d_ws + 2 * ubytes);
    float*          w2p = (float*)((char*)d_ws + 2 * ubytes + 65536);

    k_cvt_w1<<<16, 256, 0, stream>>>(W1, w1f);
    k_cvt_w2p<<<1, 128, 0, stream>>>(W2, w2p);
    k_uv<<<(nNodes + 127) / 128, 256, 0, stream>>>(x, w1f, b1, us, vs, nNodes);
    k_edge<<<(E + 63) / 64, 256, 0, stream>>>(us, vs, eli, w2p, b2, out, E, nNodes);
  } else {
    k_fallback<<<(E + 255) / 256, 512, 0, stream>>>(x, eli, W1, b1, W2, b2, out, E, nNodes);
  }
}

// Round 11
// 129.921 us; speedup vs baseline: 1.5223x; 1.1405x over previous
//
#include <hip/hip_runtime.h>
#include <hip/hip_bf16.h>
#include <stdint.h>

typedef __attribute__((ext_vector_type(8))) short s16x8;          // 8 bf16 (4 VGPRs)
typedef __attribute__((ext_vector_type(8))) unsigned short u16x8;
typedef __attribute__((ext_vector_type(4))) float f32x4;

#define D_FEAT 128
#define H2 128

__device__ __forceinline__ unsigned short f2bf(float f) {
  uint32_t u = __float_as_uint(f);
  return (unsigned short)((u + 0x7fffu + ((u >> 16) & 1u)) >> 16);  // RNE
}
__device__ __forceinline__ float bf2f(unsigned short s) {
  return __uint_as_float((uint32_t)s << 16);
}

// W1 [256][128] fp32 -> bf16 "fragment-sequential" image (64KB) in ws.
// Chunk index = (kk*8 + f)*64 + lane, lane = (g<<4)|c. Chunk holds the 8
// B-frag elements j: W1[k = kk*32 + g*8 + j][n = f*16 + c].  (R7-verified)
__global__ void k_cvt_w1(const float* __restrict__ W1, unsigned short* __restrict__ w1s) {
  int tid = blockIdx.x * blockDim.x + threadIdx.x;   // 0..4095
  int lane = tid & 63;
  int kkf  = tid >> 6;        // kk*8 + f
  int kk = kkf >> 3, f = kkf & 7;
  int c = lane & 15, g = lane >> 4;
  int n = f * 16 + c;
  u16x8 o;
#pragma unroll
  for (int j = 0; j < 8; ++j)
    o[j] = f2bf(W1[(kk * 32 + g * 8 + j) * H2 + n]);
  ((u16x8*)w1s)[tid] = o;
}

// Permuted W2 (f32): stored position s = c*8+f  <->  logical n = f*16+c.
// Matches the u/v storage permutation so the edge-stage dot is order-invariant.
__global__ void k_cvt_w2p(const float* __restrict__ W2, float* __restrict__ w2p) {
  int s = threadIdx.x;   // 0..127
  w2p[s] = W2[(s & 7) * 16 + (s >> 3)];
}

// ---------------- node precompute: u = x@W1a + b1, v = x@W1b (bf16, permuted cols) ----
__global__ __launch_bounds__(256, 4)
void k_uv(const float* __restrict__ x,
          const unsigned short* __restrict__ w1ws,
          const float* __restrict__ b1,
          unsigned short* __restrict__ u,
          unsigned short* __restrict__ v,
          int nNodes)
{
  __shared__ alignas(16) unsigned short w1t[H2 * 256];   // 64KB fragment image
  const int t0 = threadIdx.x, lane = t0 & 63, wid = t0 >> 6;
  const int c = lane & 15, g = lane >> 4;

#pragma unroll
  for (int i = 0; i < 16; ++i) {
    int idx = i * 256 + t0;
    ((u16x8*)w1t)[idx] = ((const u16x8*)w1ws)[idx];
  }

  const int nb = blockIdx.x * 128 + wid * 32;
  // A-frags: x rows (coalesced), full K=128 held (32 regs)
  s16x8 af[4][2];
#pragma unroll
  for (int m = 0; m < 2; ++m) {
    int node = nb + m * 16 + c;
    node = node < nNodes ? node : nNodes - 1;
    const float* xp = x + (size_t)node * D_FEAT;
#pragma unroll
    for (int kk = 0; kk < 4; ++kk) {
      const f32x4* q = (const f32x4*)(xp + kk * 32 + g * 8);
      f32x4 a = q[0], b = q[1];
      s16x8 vv;
      vv[0] = (short)f2bf(a[0]); vv[1] = (short)f2bf(a[1]);
      vv[2] = (short)f2bf(a[2]); vv[3] = (short)f2bf(a[3]);
      vv[4] = (short)f2bf(b[0]); vv[5] = (short)f2bf(b[1]);
      vv[6] = (short)f2bf(b[2]); vv[7] = (short)f2bf(b[3]);
      af[kk][m] = vv;
    }
  }
  float b1v[8];
#pragma unroll
  for (int f = 0; f < 8; ++f) b1v[f] = b1[f * 16 + c];

  __syncthreads();
  const unsigned short* bbase = w1t + (unsigned)lane * 8;   // lane*16B

  f32x4 acc[2][8];

  // ---- u pass: acc init = b1 (C-in is the bias), K chunks 0..3 ----
#pragma unroll
  for (int m = 0; m < 2; ++m)
#pragma unroll
    for (int f = 0; f < 8; ++f) {
      f32x4 z = {b1v[f], b1v[f], b1v[f], b1v[f]};
      acc[m][f] = z;
    }
#pragma unroll
  for (int kk = 0; kk < 4; ++kk)
#pragma unroll
    for (int f = 0; f < 8; ++f) {
      s16x8 bfrag = *(const s16x8*)(bbase + (kk * 8 + f) * 512);
#pragma unroll
      for (int m = 0; m < 2; ++m)
        acc[m][f] = __builtin_amdgcn_mfma_f32_16x16x32_bf16(af[kk][m], bfrag, acc[m][f], 0, 0, 0);
    }
#pragma unroll
  for (int m = 0; m < 2; ++m)
#pragma unroll
    for (int r = 0; r < 4; ++r) {
      int node = nb + m * 16 + g * 4 + r;     // D row = g*4+r within 16-tile
      if (node < nNodes) {
        u16x8 o;
#pragma unroll
        for (int f = 0; f < 8; ++f) o[f] = f2bf(acc[m][f][r]);
        *(u16x8*)(u + (size_t)node * H2 + c * 8) = o;   // stored cols c*8..c*8+7
      }
    }

  // ---- v pass: acc init = 0, K chunks 4..7 (same x A-frags) ----
#pragma unroll
  for (int m = 0; m < 2; ++m)
#pragma unroll
    for (int f = 0; f < 8; ++f) {
      f32x4 z = {0.f, 0.f, 0.f, 0.f};
      acc[m][f] = z;
    }
#pragma unroll
  for (int kk = 0; kk < 4; ++kk)
#pragma unroll
    for (int f = 0; f < 8; ++f) {
      s16x8 bfrag = *(const s16x8*)(bbase + ((kk + 4) * 8 + f) * 512);
#pragma unroll
      for (int m = 0; m < 2; ++m)
        acc[m][f] = __builtin_amdgcn_mfma_f32_16x16x32_bf16(af[kk][m], bfrag, acc[m][f], 0, 0, 0);
    }
#pragma unroll
  for (int m = 0; m < 2; ++m)
#pragma unroll
    for (int r = 0; r < 4; ++r) {
      int node = nb + m * 16 + g * 4 + r;
      if (node < nNodes) {
        u16x8 o;
#pragma unroll
        for (int f = 0; f < 8; ++f) o[f] = f2bf(acc[m][f][r]);
        *(u16x8*)(v + (size_t)node * H2 + c * 8) = o;
      }
    }
}

// ---------------- edge stage v2: whole-row-per-instruction gathers ----------------
// Wave = 8 edges: lane = eo*16 + p (eo: edge-in-group 0..3, p: 16B chunk 0..15).
// One load instr covers a full 256B u/v row (16 lanes x 16B contiguous) ->
// TCP coalesces to 2x128B line requests: 4 L2 requests/edge (was 8).
__global__ __launch_bounds__(256, 8)
void k_edge(const unsigned short* __restrict__ u,
            const unsigned short* __restrict__ v,
            const int* __restrict__ eli,
            const float* __restrict__ w2p,
            const float* __restrict__ b2,
            float* __restrict__ out, int E, int nNodes)
{
  const int t0 = threadIdx.x, lane = t0 & 63, wid = t0 >> 6;
  const int p  = lane & 15;       // 16B chunk within row
  const int eo = lane >> 4;       // edge within 4-group
  const int ewave = blockIdx.x * 32 + wid * 8;

  u16x8 uu[2], vv[2];
  int eidx[2];
#pragma unroll
  for (int m = 0; m < 2; ++m) {
    int e = ewave + m * 4 + eo;
    eidx[m] = e;
    int ec = e < E ? e : E - 1;
    int nr = eli[ec], nc = eli[E + ec];
    nr = nr < 0 ? 0 : (nr >= nNodes ? nNodes - 1 : nr);
    nc = nc < 0 ? 0 : (nc >= nNodes ? nNodes - 1 : nc);
    uu[m] = *(const u16x8*)(u + (size_t)nr * H2 + p * 8);
    vv[m] = *(const u16x8*)(v + (size_t)nc * H2 + p * 8);
  }

  // lane's 8 W2 coefficients in stored order (32B, L1-resident)
  const f32x4* wq = (const f32x4*)(w2p + p * 8);
  const f32x4 w0 = wq[0], w1 = wq[1];
  const float b2s = b2[0];

#pragma unroll
  for (int m = 0; m < 2; ++m) {
    float s = 0.f;
#pragma unroll
    for (int j = 0; j < 8; ++j) {
      float h = bf2f(uu[m][j]) + bf2f(vv[m][j]);
      h = h > 0.f ? h : 0.f;
      float w = (j < 4) ? w0[j & 3] : w1[j & 3];
      s += h * w;
    }
    // reduce over the 16 p-lanes of this edge
    s += __shfl_xor(s, 1, 64);
    s += __shfl_xor(s, 2, 64);
    s += __shfl_xor(s, 4, 64);
    s += __shfl_xor(s, 8, 64);
    if (p == 0 && eidx[m] < E) out[eidx[m]] = s + b2s;
  }
}

// ---------------- fallback (ws too small): R7 monolithic, fp32 paths ----------------
__global__ __launch_bounds__(512, 4)
void k_fallback(const float* __restrict__ xf,
                const int* __restrict__ eli,
                const float* __restrict__ W1,
                const float* __restrict__ b1,
                const float* __restrict__ W2,
                const float* __restrict__ b2,
                float* __restrict__ out, int E, int nNodes)
{
  __shared__ alignas(16) unsigned short w1t[H2 * 256];
  const int t0 = threadIdx.x, lane = t0 & 63, wid = t0 >> 6;
  const int c = lane & 15, g = lane >> 4;

#pragma unroll
  for (int i = 0; i < 8; ++i) {
    int chunk = i * 512 + t0;
    int cl = chunk & 63, kkf = chunk >> 6;
    int kk = kkf >> 3, f = kkf & 7;
    int cc = cl & 15, gg = cl >> 4;
    int n = f * 16 + cc;
    u16x8 o;
#pragma unroll
    for (int j = 0; j < 8; ++j)
      o[j] = f2bf(W1[(kk * 32 + gg * 8 + j) * H2 + n]);
    ((u16x8*)w1t)[chunk] = o;
  }

  const int gbase = blockIdx.x * 256 + wid * 32;
  unsigned ro[2], co[2];
#pragma unroll
  for (int m = 0; m < 2; ++m) {
    int e = gbase + m * 16 + c;
    e = e < E ? e : E - 1;
    int nr = eli[e], nc = eli[E + e];
    nr = nr < 0 ? 0 : (nr >= nNodes ? nNodes - 1 : nr);
    nc = nc < 0 ? 0 : (nc >= nNodes ? nNodes - 1 : nc);
    ro[m] = (unsigned)nr * D_FEAT + g * 8;
    co[m] = (unsigned)nc * D_FEAT + g * 8;
  }
  __syncthreads();

  auto loadA = [&](int kk, s16x8* dst) {
#pragma unroll
    for (int m = 0; m < 2; ++m) {
      unsigned off = (kk < 4 ? ro[m] : co[m]) + (unsigned)((kk & 3) * 32);
      const f32x4* q = (const f32x4*)(xf + off);
      f32x4 a = q[0], b = q[1];
      s16x8 vv2;
      vv2[0] = (short)f2bf(a[0]); vv2[1] = (short)f2bf(a[1]);
      vv2[2] = (short)f2bf(a[2]); vv2[3] = (short)f2bf(a[3]);
      vv2[4] = (short)f2bf(b[0]); vv2[5] = (short)f2bf(b[1]);
      vv2[6] = (short)f2bf(b[2]); vv2[7] = (short)f2bf(b[3]);
      dst[m] = vv2;
    }
  };

  f32x4 acc[2][8];
#pragma unroll
  for (int m = 0; m < 2; ++m)
#pragma unroll
    for (int f = 0; f < 8; ++f) {
      f32x4 z = {0.f, 0.f, 0.f, 0.f};
      acc[m][f] = z;
    }
  s16x8 abuf[2][2];
  loadA(0, abuf[0]);
  loadA(1, abuf[1]);
  const unsigned short* bbase = w1t + (unsigned)lane * 8;
#pragma unroll
  for (int kk = 0; kk < 8; ++kk) {
#pragma unroll
    for (int f = 0; f < 8; ++f) {
      s16x8 bfrag = *(const s16x8*)(bbase + (kk * 8 + f) * 512);
#pragma unroll
      for (int m = 0; m < 2; ++m)
        acc[m][f] = __builtin_amdgcn_mfma_f32_16x16x32_bf16(abuf[kk & 1][m], bfrag, acc[m][f], 0, 0, 0);
    }
    if (kk < 6) loadA(kk + 2, abuf[kk & 1]);
  }
  float b1v[8], w2v[8];
#pragma unroll
  for (int f = 0; f < 8; ++f) { b1v[f] = b1[f * 16 + c]; w2v[f] = W2[f * 16 + c]; }
  const float b2s = b2[0];
#pragma unroll
  for (int m = 0; m < 2; ++m) {
    float sr[4];
#pragma unroll
    for (int r = 0; r < 4; ++r) {
      float s = 0.f;
#pragma unroll
      for (int f = 0; f < 8; ++f) {
        float h = acc[m][f][r] + b1v[f];
        h = h > 0.f ? h : 0.f;
        s += h * w2v[f];
      }
#pragma unroll
      for (int msk = 1; msk < 16; msk <<= 1) s += __shfl_xor(s, msk, 64);
      sr[r] = s;
    }
    int ebase2 = gbase + m * 16 + g * 4;
    if (c == 0 && ebase2 < E) {
      f32x4 o = {sr[0] + b2s, sr[1] + b2s, sr[2] + b2s, sr[3] + b2s};
      *(f32x4*)(out + ebase2) = o;
    }
  }
}

extern "C" void kernel_launch(void* const* d_in, const int* in_sizes, int n_in,
                              void* d_out, int out_size, void* d_ws, size_t ws_size,
                              hipStream_t stream) {
  const float* x   = (const float*)d_in[0];
  const int*   eli = (const int*)d_in[1];     // int32 per harness contract
  const float* W1  = (const float*)d_in[2];
  const float* b1  = (const float*)d_in[3];
  const float* W2  = (const float*)d_in[4];
  const float* b2  = (const float*)d_in[5];
  float* out = (float*)d_out;

  const int E      = in_sizes[1] / 2;
  const int nNodes = in_sizes[0] / D_FEAT;

  const size_t ubytes = (size_t)nNodes * H2 * 2;      // 25.6MB each
  const size_t need   = 2 * ubytes + 65536 + 512;

  if (ws_size >= need) {
    unsigned short* us  = (unsigned short*)d_ws;
    unsigned short* vs  = (unsigned short*)((char*)d_ws + ubytes);
    unsigned short* w1f = (unsigned short*)((char*)d_ws + 2 * ubytes);
    float*          w2p = (float*)((char*)d_ws + 2 * ubytes + 65536);

    k_cvt_w1<<<16, 256, 0, stream>>>(W1, w1f);
    k_cvt_w2p<<<1, 128, 0, stream>>>(W2, w2p);
    k_uv<<<(nNodes + 127) / 128, 256, 0, stream>>>(x, w1f, b1, us, vs, nNodes);
    k_edge<<<(E + 31) / 32, 256, 0, stream>>>(us, vs, eli, w2p, b2, out, E, nNodes);
  } else {
    k_fallback<<<(E + 255) / 256, 512, 0, stream>>>(x, eli, W1, b1, W2, b2, out, E, nNodes);
  }
}